// Round 1
// baseline (927.380 us; speedup 1.0000x reference)
//
#include <hip/hip_runtime.h>
#include <math.h>

#define P_ 1936   // 44*44
#define EPS_ 1e-5f

// ---------------- depth transpose: dT[b][p][c] = depth[b][c][p] ----------------
__global__ __launch_bounds__(256) void k_tdepth(const float* __restrict__ depth,
                                                float* __restrict__ dT) {
    __shared__ float buf[64][65];
    const int b = blockIdx.y;
    const int p0 = blockIdx.x * 64;
    const int t = threadIdx.x;
    {
        const int pl = t & 63;
        const int cg = (t >> 6) * 16;
        #pragma unroll
        for (int i = 0; i < 16; ++i) {
            int c = cg + i;
            int p = p0 + pl;
            buf[c][pl] = (p < P_) ? depth[((size_t)b*64 + c)*P_ + p] : 0.f;
        }
    }
    __syncthreads();
    {
        const int cc = t & 63;
        const int pg = (t >> 6) * 16;
        #pragma unroll
        for (int i = 0; i < 16; ++i) {
            int p = p0 + pg + i;
            if (p < P_) dT[((size_t)b*P_ + p)*64 + cc] = buf[cc][pg + i];
        }
    }
}

// ---------------- h_c conv: relu(conv3x3(concat(rgb,depth), w_hc)+b_hc), pad=1 ----------------
// grid (4 row-quarters, 8 o-groups, 16 b), block 256
__global__ __launch_bounds__(256) void k_hc(const float* __restrict__ rgb,
                                            const float* __restrict__ depth,
                                            const float* __restrict__ whc,
                                            const float* __restrict__ bhc,
                                            float* __restrict__ hc) {
    __shared__ float tile[13*46];
    const int q = blockIdx.x, og = blockIdx.y, b = blockIdx.z;
    const int r0 = q * 11;
    const int t = threadIdx.x;
    float acc[8][2];
    #pragma unroll
    for (int oo = 0; oo < 8; ++oo) { acc[oo][0] = 0.f; acc[oo][1] = 0.f; }

    for (int c = 0; c < 128; ++c) {
        const float* src = (c < 64) ? (rgb + ((size_t)b*64 + c)*P_)
                                    : (depth + ((size_t)b*64 + (c-64))*P_);
        __syncthreads();
        for (int idx = t; idx < 13*46; idx += 256) {
            int ly = idx / 46, lx = idx - ly*46;
            int gy = r0 - 1 + ly, gx = lx - 1;
            tile[idx] = (gy >= 0 && gy < 44 && gx >= 0 && gx < 44) ? src[gy*44 + gx] : 0.f;
        }
        __syncthreads();
        const float* wp = whc + ((size_t)(og*8)*128 + c)*9;
        float wv[8][9];
        #pragma unroll
        for (int oo = 0; oo < 8; ++oo)
            #pragma unroll
            for (int k = 0; k < 9; ++k)
                wv[oo][k] = wp[(size_t)oo*1152 + k];
        #pragma unroll
        for (int s = 0; s < 2; ++s) {
            int px = t + s*256;
            if (px < 484) {
                int row = px / 44, col = px - row*44;
                float nb[9];
                #pragma unroll
                for (int ky = 0; ky < 3; ++ky)
                    #pragma unroll
                    for (int kx = 0; kx < 3; ++kx)
                        nb[ky*3+kx] = tile[(row+ky)*46 + col + kx];
                #pragma unroll
                for (int oo = 0; oo < 8; ++oo) {
                    float a = acc[oo][s];
                    #pragma unroll
                    for (int k = 0; k < 9; ++k) a = fmaf(nb[k], wv[oo][k], a);
                    acc[oo][s] = a;
                }
            }
        }
    }
    #pragma unroll
    for (int s = 0; s < 2; ++s) {
        int px = t + s*256;
        if (px < 484) {
            int row = px / 44, col = px - row*44;
            #pragma unroll
            for (int oo = 0; oo < 8; ++oo) {
                int o = og*8 + oo;
                hc[(((size_t)b*64 + o)*44 + (r0+row))*44 + col] = fmaxf(acc[oo][s] + bhc[o], 0.f);
            }
        }
    }
}

// ---------------- depth_corr[b][c] = sum_hw rgb*depth ----------------
__global__ __launch_bounds__(64) void k_dcorr(const float* __restrict__ rgb,
                                              const float* __restrict__ depth,
                                              float* __restrict__ dcorr) {
    const int c = blockIdx.x, b = blockIdx.y, lane = threadIdx.x;
    const float* r = rgb + ((size_t)b*64 + c)*P_;
    const float* d = depth + ((size_t)b*64 + c)*P_;
    float acc = 0.f;
    for (int p = lane; p < P_; p += 64) acc = fmaf(r[p], d[p], acc);
    #pragma unroll
    for (int off = 32; off > 0; off >>= 1) acc += __shfl_down(acc, off, 64);
    if (lane == 0) dcorr[b*64 + c] = acc;
}

// ---------------- channel attention MLP: catt = sigmoid(2*mlp(dcorr)) ----------------
__global__ __launch_bounds__(64) void k_mlp(const float* __restrict__ dcorr,
                                            const float* __restrict__ wl1,
                                            const float* __restrict__ bl1,
                                            const float* __restrict__ wl2,
                                            const float* __restrict__ bl2,
                                            float* __restrict__ catt) {
    __shared__ float dc[64], h[16];
    const int b = blockIdx.x, t = threadIdx.x;
    dc[t] = dcorr[b*64 + t];
    __syncthreads();
    if (t < 16) {
        float a = bl1[t];
        #pragma unroll 8
        for (int c = 0; c < 64; ++c) a = fmaf(dc[c], wl1[t*64 + c], a);
        h[t] = fmaxf(a, 0.f);
    }
    __syncthreads();
    float m = bl2[t];
    #pragma unroll
    for (int j = 0; j < 16; ++j) m = fmaf(h[j], wl2[t*16 + j], m);
    catt[b*64 + t] = 1.f / (1.f + expf(-2.f*m));
}

// ---------------- U[b][o][kk][c] = sum_p w_s1[o][p][kk] * depth[b][c][p] ----------------
// grid (32 o, 16 b), block 256: lane = c, wave = p-quarter
__global__ __launch_bounds__(256) void k_U(const float* __restrict__ dT,
                                           const float* __restrict__ ws1,
                                           float* __restrict__ U) {
    __shared__ float red[4*9*64];
    const int o = blockIdx.x, b = blockIdx.y;
    const int t = threadIdx.x, lane = t & 63, qw = t >> 6;
    float acc[9];
    #pragma unroll
    for (int k = 0; k < 9; ++k) acc[k] = 0.f;
    const float* dp = dT + (size_t)b*P_*64 + lane;
    const float* wbase = ws1 + (size_t)o*P_*9;
    const int p0 = qw*484, p1 = p0 + 484;
    #pragma unroll 4
    for (int p = p0; p < p1; ++p) {
        float d = dp[(size_t)p*64];
        const float* wp = wbase + (size_t)p*9;
        #pragma unroll
        for (int k = 0; k < 9; ++k) acc[k] = fmaf(d, wp[k], acc[k]);
    }
    #pragma unroll
    for (int k = 0; k < 9; ++k) red[(qw*9 + k)*64 + lane] = acc[k];
    __syncthreads();
    for (int s = t; s < 576; s += 256) {
        int kk = s >> 6, c = s & 63;
        float v = red[kk*64 + c] + red[(9+kk)*64 + c] + red[(18+kk)*64 + c] + red[(27+kk)*64 + c];
        U[(((size_t)b*32 + o)*9 + kk)*64 + c] = v;
    }
}

// ---------------- conv1: z1 = conv3x3_valid(pixel_corr, w_s1) via per-batch weights U ----------------
// grid (2 row-halves of 21, 8 o-groups of 4, 16 b)
__global__ __launch_bounds__(256) void k_conv1(const float* __restrict__ rgb,
                                               const float* __restrict__ U,
                                               const float* __restrict__ bs1,
                                               float* __restrict__ z1) {
    __shared__ float tile[23*44];
    const int half = blockIdx.x, og = blockIdx.y, b = blockIdx.z;
    const int r0 = half * 21;
    const int t = threadIdx.x;
    float acc[4][4];
    #pragma unroll
    for (int oo = 0; oo < 4; ++oo)
        #pragma unroll
        for (int s = 0; s < 4; ++s) acc[oo][s] = 0.f;

    for (int c = 0; c < 64; ++c) {
        const float* src = rgb + ((size_t)b*64 + c)*P_ + r0*44;
        __syncthreads();
        for (int idx = t; idx < 23*44; idx += 256) tile[idx] = src[idx];
        __syncthreads();
        float wv[4][9];
        #pragma unroll
        for (int oo = 0; oo < 4; ++oo) {
            const float* up = U + (((size_t)b*32 + og*4 + oo)*9)*64 + c;
            #pragma unroll
            for (int k = 0; k < 9; ++k) wv[oo][k] = up[k*64];
        }
        #pragma unroll
        for (int s = 0; s < 4; ++s) {
            int px = t + s*256;
            if (px < 882) {
                int row = px / 42, col = px - row*42;
                float nb[9];
                #pragma unroll
                for (int ky = 0; ky < 3; ++ky)
                    #pragma unroll
                    for (int kx = 0; kx < 3; ++kx)
                        nb[ky*3+kx] = tile[(row+ky)*44 + col + kx];
                #pragma unroll
                for (int oo = 0; oo < 4; ++oo) {
                    float a = acc[oo][s];
                    #pragma unroll
                    for (int k = 0; k < 9; ++k) a = fmaf(nb[k], wv[oo][k], a);
                    acc[oo][s] = a;
                }
            }
        }
    }
    #pragma unroll
    for (int s = 0; s < 4; ++s) {
        int px = t + s*256;
        if (px < 882) {
            int row = px / 42, col = px - row*42;
            #pragma unroll
            for (int oo = 0; oo < 4; ++oo) {
                int o = og*4 + oo;
                z1[(((size_t)b*32 + o)*42 + (r0+row))*42 + col] = acc[oo][s] + bs1[o];
            }
        }
    }
}

// ---------------- BN stats: per-channel sum & sumsq (32 channels) ----------------
__global__ __launch_bounds__(256) void k_stats(const float* __restrict__ z, int npix,
                                               float* __restrict__ stats) {
    __shared__ float s1[256], s2[256];
    const int ch = blockIdx.x, t = threadIdx.x;
    float sum = 0.f, sq = 0.f;
    for (int b = 0; b < 16; ++b) {
        const float* p = z + ((size_t)b*32 + ch)*npix;
        for (int i = t; i < npix; i += 256) {
            float v = p[i];
            sum += v; sq = fmaf(v, v, sq);
        }
    }
    s1[t] = sum; s2[t] = sq;
    __syncthreads();
    for (int off = 128; off > 0; off >>= 1) {
        if (t < off) { s1[t] += s1[t+off]; s2[t] += s2[t+off]; }
        __syncthreads();
    }
    if (t == 0) { stats[ch*2] = s1[0]; stats[ch*2+1] = s2[0]; }
}

__device__ __forceinline__ void bn_coef(const float* stats, const float* g,
                                        const float* be, int ch, float inv_n,
                                        float& sc, float& sh) {
    float sum = stats[ch*2], sq = stats[ch*2+1];
    float mu = sum * inv_n;
    float var = sq * inv_n - mu*mu;
    float r = rsqrtf(var + EPS_);
    sc = g[ch] * r;
    sh = be[ch] - mu * sc;
}

// ---------------- conv2: 42->40, input = relu(bn1(z1)) ----------------
// grid (2 halves of 20, 8 o-groups of 4, 16 b)
__global__ __launch_bounds__(256) void k_conv2(const float* __restrict__ z1,
                                               const float* __restrict__ ws2,
                                               const float* __restrict__ bs2,
                                               const float* __restrict__ g,
                                               const float* __restrict__ be,
                                               const float* __restrict__ stats,
                                               float* __restrict__ z2) {
    __shared__ float tile[22*42];
    const int half = blockIdx.x, og = blockIdx.y, b = blockIdx.z;
    const int r0 = half * 20;
    const int t = threadIdx.x;
    const float inv_n = 1.f / 28224.f;
    float acc[4][4];
    #pragma unroll
    for (int oo = 0; oo < 4; ++oo)
        #pragma unroll
        for (int s = 0; s < 4; ++s) acc[oo][s] = 0.f;

    for (int c = 0; c < 32; ++c) {
        float sc, sh;
        bn_coef(stats, g, be, c, inv_n, sc, sh);
        const float* src = z1 + ((size_t)b*32 + c)*1764 + r0*42;
        __syncthreads();
        for (int idx = t; idx < 22*42; idx += 256)
            tile[idx] = fmaxf(fmaf(src[idx], sc, sh), 0.f);
        __syncthreads();
        float wv[4][9];
        #pragma unroll
        for (int oo = 0; oo < 4; ++oo) {
            const float* wp = ws2 + ((size_t)(og*4 + oo)*32 + c)*9;
            #pragma unroll
            for (int k = 0; k < 9; ++k) wv[oo][k] = wp[k];
        }
        #pragma unroll
        for (int s = 0; s < 4; ++s) {
            int px = t + s*256;
            if (px < 800) {
                int row = px / 40, col = px - row*40;
                float nb[9];
                #pragma unroll
                for (int ky = 0; ky < 3; ++ky)
                    #pragma unroll
                    for (int kx = 0; kx < 3; ++kx)
                        nb[ky*3+kx] = tile[(row+ky)*42 + col + kx];
                #pragma unroll
                for (int oo = 0; oo < 4; ++oo) {
                    float a = acc[oo][s];
                    #pragma unroll
                    for (int k = 0; k < 9; ++k) a = fmaf(nb[k], wv[oo][k], a);
                    acc[oo][s] = a;
                }
            }
        }
    }
    #pragma unroll
    for (int s = 0; s < 4; ++s) {
        int px = t + s*256;
        if (px < 800) {
            int row = px / 40, col = px - row*40;
            #pragma unroll
            for (int oo = 0; oo < 4; ++oo) {
                int o = og*4 + oo;
                z2[(((size_t)b*32 + o)*40 + (r0+row))*40 + col] = acc[oo][s] + bs2[o];
            }
        }
    }
}

// ---------------- convT1: 40->42, input = relu(bn2(z2)), w_d1 [in][out][3][3] ----------------
// y[o,i,j] = sum_{c,u,v} x[c,i-u,j-v]*w[c,o,u,v]
// grid (2 halves of 21, 8 o-groups of 4, 16 b)
__global__ __launch_bounds__(256) void k_dconv1(const float* __restrict__ z2,
                                                const float* __restrict__ wd1,
                                                const float* __restrict__ bd1,
                                                const float* __restrict__ g,
                                                const float* __restrict__ be,
                                                const float* __restrict__ stats,
                                                float* __restrict__ z3) {
    __shared__ float tile[23*44];
    const int half = blockIdx.x, og = blockIdx.y, b = blockIdx.z;
    const int r0 = half * 21;
    const int t = threadIdx.x;
    const float inv_n = 1.f / 25600.f;
    float acc[4][4];
    #pragma unroll
    for (int oo = 0; oo < 4; ++oo)
        #pragma unroll
        for (int s = 0; s < 4; ++s) acc[oo][s] = 0.f;

    for (int c = 0; c < 32; ++c) {
        float sc, sh;
        bn_coef(stats, g, be, c, inv_n, sc, sh);
        const float* src = z2 + ((size_t)b*32 + c)*1600;
        __syncthreads();
        for (int idx = t; idx < 23*44; idx += 256) {
            int ly = idx / 44, lx = idx - ly*44;
            int gy = r0 - 2 + ly, gx = lx - 2;
            float v = 0.f;
            if (gy >= 0 && gy < 40 && gx >= 0 && gx < 40)
                v = fmaxf(fmaf(src[gy*40 + gx], sc, sh), 0.f);
            tile[idx] = v;
        }
        __syncthreads();
        float wv[4][9];
        #pragma unroll
        for (int oo = 0; oo < 4; ++oo) {
            const float* wp = wd1 + ((size_t)c*32 + og*4 + oo)*9;
            #pragma unroll
            for (int m = 0; m < 9; ++m) wv[oo][m] = wp[m];
        }
        #pragma unroll
        for (int s = 0; s < 4; ++s) {
            int px = t + s*256;
            if (px < 882) {
                int row = px / 42, col = px - row*42;
                float nb[9];
                #pragma unroll
                for (int u = 0; u < 3; ++u)
                    #pragma unroll
                    for (int v = 0; v < 3; ++v)
                        nb[u*3+v] = tile[(row + 2 - u)*44 + (col + 2 - v)];
                #pragma unroll
                for (int oo = 0; oo < 4; ++oo) {
                    float a = acc[oo][s];
                    #pragma unroll
                    for (int m = 0; m < 9; ++m) a = fmaf(nb[m], wv[oo][m], a);
                    acc[oo][s] = a;
                }
            }
        }
    }
    #pragma unroll
    for (int s = 0; s < 4; ++s) {
        int px = t + s*256;
        if (px < 882) {
            int row = px / 42, col = px - row*42;
            #pragma unroll
            for (int oo = 0; oo < 4; ++oo) {
                int o = og*4 + oo;
                z3[(((size_t)b*32 + o)*42 + (r0+row))*42 + col] = acc[oo][s] + bd1[o];
            }
        }
    }
}

// ---------------- convT2: 42->44, input = relu(bn3(z3)), 1 output channel, sigmoid ----------------
// grid (2 halves of 22, 16 b)
__global__ __launch_bounds__(256) void k_dconv2(const float* __restrict__ z3,
                                                const float* __restrict__ wd2,
                                                const float* __restrict__ bd2,
                                                const float* __restrict__ g,
                                                const float* __restrict__ be,
                                                const float* __restrict__ stats,
                                                float* __restrict__ satt) {
    __shared__ float tile[24*46];
    const int half = blockIdx.x, b = blockIdx.y;
    const int r0 = half * 22;
    const int t = threadIdx.x;
    const float inv_n = 1.f / 28224.f;
    float acc[4] = {0.f, 0.f, 0.f, 0.f};

    for (int c = 0; c < 32; ++c) {
        float sc, sh;
        bn_coef(stats, g, be, c, inv_n, sc, sh);
        const float* src = z3 + ((size_t)b*32 + c)*1764;
        __syncthreads();
        for (int idx = t; idx < 24*46; idx += 256) {
            int ly = idx / 46, lx = idx - ly*46;
            int gy = r0 - 2 + ly, gx = lx - 2;
            float v = 0.f;
            if (gy >= 0 && gy < 42 && gx >= 0 && gx < 42)
                v = fmaxf(fmaf(src[gy*42 + gx], sc, sh), 0.f);
            tile[idx] = v;
        }
        __syncthreads();
        float w9[9];
        #pragma unroll
        for (int m = 0; m < 9; ++m) w9[m] = wd2[c*9 + m];
        #pragma unroll
        for (int s = 0; s < 4; ++s) {
            int px = t + s*256;
            if (px < 968) {
                int row = px / 44, col = px - row*44;
                float a = acc[s];
                #pragma unroll
                for (int u = 0; u < 3; ++u)
                    #pragma unroll
                    for (int v = 0; v < 3; ++v)
                        a = fmaf(tile[(row + 2 - u)*46 + (col + 2 - v)], w9[u*3+v], a);
                acc[s] = a;
            }
        }
    }
    const float bb = bd2[0];
    #pragma unroll
    for (int s = 0; s < 4; ++s) {
        int px = t + s*256;
        if (px < 968) {
            int row = px / 44, col = px - row*44;
            float v = acc[s] + bb;
            satt[(size_t)b*P_ + (r0+row)*44 + col] = 1.f / (1.f + expf(-v));
        }
    }
}

// ---------------- final conv: relu(conv3x3(h_att, w_hf)+b_hf), pad=1 ----------------
// h_att[c<64] = hc[c]*satt (per-pixel); h_att[c>=64] = hc[c-64]*catt[c-64] (scalar)
// grid (4 row-quarters, 8 o-groups, 16 b)
__global__ __launch_bounds__(256) void k_final(const float* __restrict__ hc,
                                               const float* __restrict__ satt,
                                               const float* __restrict__ catt,
                                               const float* __restrict__ whf,
                                               const float* __restrict__ bhf,
                                               float* __restrict__ out) {
    __shared__ float tile[13*46];
    const int q = blockIdx.x, og = blockIdx.y, b = blockIdx.z;
    const int r0 = q * 11;
    const int t = threadIdx.x;
    float acc[8][2];
    #pragma unroll
    for (int oo = 0; oo < 8; ++oo) { acc[oo][0] = 0.f; acc[oo][1] = 0.f; }

    for (int c = 0; c < 128; ++c) {
        const int cm = c & 63;
        const float* src = hc + ((size_t)b*64 + cm)*P_;
        const float cav = catt[b*64 + cm];
        const bool spat = (c < 64);
        __syncthreads();
        for (int idx = t; idx < 13*46; idx += 256) {
            int ly = idx / 46, lx = idx - ly*46;
            int gy = r0 - 1 + ly, gx = lx - 1;
            float v = 0.f;
            if (gy >= 0 && gy < 44 && gx >= 0 && gx < 44) {
                v = src[gy*44 + gx];
                v *= spat ? satt[(size_t)b*P_ + gy*44 + gx] : cav;
            }
            tile[idx] = v;
        }
        __syncthreads();
        const float* wp = whf + ((size_t)(og*8)*128 + c)*9;
        float wv[8][9];
        #pragma unroll
        for (int oo = 0; oo < 8; ++oo)
            #pragma unroll
            for (int k = 0; k < 9; ++k)
                wv[oo][k] = wp[(size_t)oo*1152 + k];
        #pragma unroll
        for (int s = 0; s < 2; ++s) {
            int px = t + s*256;
            if (px < 484) {
                int row = px / 44, col = px - row*44;
                float nb[9];
                #pragma unroll
                for (int ky = 0; ky < 3; ++ky)
                    #pragma unroll
                    for (int kx = 0; kx < 3; ++kx)
                        nb[ky*3+kx] = tile[(row+ky)*46 + col + kx];
                #pragma unroll
                for (int oo = 0; oo < 8; ++oo) {
                    float a = acc[oo][s];
                    #pragma unroll
                    for (int k = 0; k < 9; ++k) a = fmaf(nb[k], wv[oo][k], a);
                    acc[oo][s] = a;
                }
            }
        }
    }
    #pragma unroll
    for (int s = 0; s < 2; ++s) {
        int px = t + s*256;
        if (px < 484) {
            int row = px / 44, col = px - row*44;
            #pragma unroll
            for (int oo = 0; oo < 8; ++oo) {
                int o = og*8 + oo;
                out[(((size_t)b*64 + o)*44 + (r0+row))*44 + col] = fmaxf(acc[oo][s] + bhf[o], 0.f);
            }
        }
    }
}

extern "C" void kernel_launch(void* const* d_in, const int* in_sizes, int n_in,
                              void* d_out, int out_size, void* d_ws, size_t ws_size,
                              hipStream_t stream) {
    const float* depth = (const float*)d_in[0];
    const float* rgb   = (const float*)d_in[1];
    const float* w_hc  = (const float*)d_in[2];
    const float* b_hc  = (const float*)d_in[3];
    const float* w_hf  = (const float*)d_in[4];
    const float* b_hf  = (const float*)d_in[5];
    const float* w_s1  = (const float*)d_in[6];
    const float* bs1   = (const float*)d_in[7];
    const float* g1    = (const float*)d_in[8];
    const float* be1   = (const float*)d_in[9];
    const float* w_s2  = (const float*)d_in[10];
    const float* bs2   = (const float*)d_in[11];
    const float* g2    = (const float*)d_in[12];
    const float* be2   = (const float*)d_in[13];
    const float* w_d1  = (const float*)d_in[14];
    const float* bd1   = (const float*)d_in[15];
    const float* g3    = (const float*)d_in[16];
    const float* be3   = (const float*)d_in[17];
    const float* w_d2  = (const float*)d_in[18];
    const float* bd2   = (const float*)d_in[19];
    const float* w_l1  = (const float*)d_in[20];
    const float* bl1   = (const float*)d_in[21];
    const float* w_l2  = (const float*)d_in[22];
    const float* bl2   = (const float*)d_in[23];

    float* out = (float*)d_out;
    float* ws  = (float*)d_ws;

    float* hc    = ws;                 // 16*64*1936 = 1,982,464
    float* dT    = hc   + 1982464;     // 16*1936*64 = 1,982,464
    float* U     = dT   + 1982464;     // 16*288*64  = 294,912
    float* z1    = U    + 294912;      // 16*32*42*42 = 903,168
    float* z2    = z1   + 903168;      // 16*32*40*40 = 819,200
    float* z3    = z2   + 819200;      // 16*32*42*42 = 903,168
    float* satt  = z3   + 903168;      // 16*44*44 = 30,976
    float* catt  = satt + 30976;       // 16*64
    float* dcor  = catt + 1024;        // 16*64
    float* stats = dcor + 1024;        // 3*64

    k_tdepth<<<dim3(31,16), 256, 0, stream>>>(depth, dT);
    k_hc<<<dim3(4,8,16), 256, 0, stream>>>(rgb, depth, w_hc, b_hc, hc);
    k_dcorr<<<dim3(64,16), 64, 0, stream>>>(rgb, depth, dcor);
    k_mlp<<<16, 64, 0, stream>>>(dcor, w_l1, bl1, w_l2, bl2, catt);
    k_U<<<dim3(32,16), 256, 0, stream>>>(dT, w_s1, U);
    k_conv1<<<dim3(2,8,16), 256, 0, stream>>>(rgb, U, bs1, z1);
    k_stats<<<32, 256, 0, stream>>>(z1, 1764, stats);
    k_conv2<<<dim3(2,8,16), 256, 0, stream>>>(z1, w_s2, bs2, g1, be1, stats, z2);
    k_stats<<<32, 256, 0, stream>>>(z2, 1600, stats + 64);
    k_dconv1<<<dim3(2,8,16), 256, 0, stream>>>(z2, w_d1, bd1, g2, be2, stats + 64, z3);
    k_stats<<<32, 256, 0, stream>>>(z3, 1764, stats + 128);
    k_dconv2<<<dim3(2,16), 256, 0, stream>>>(z3, w_d2, bd2, g3, be3, stats + 128, satt);
    k_final<<<dim3(4,8,16), 256, 0, stream>>>(hc, satt, catt, w_hf, b_hf, out);
}

// Round 2
// 586.455 us; speedup vs baseline: 1.5813x; 1.5813x over previous
//
#include <hip/hip_runtime.h>
#include <math.h>

#define P_ 1936   // 44*44
#define EPS_ 1e-5f

typedef __attribute__((ext_vector_type(8))) short bf16x8;
typedef __attribute__((ext_vector_type(4))) float f32x4;

__device__ __forceinline__ ushort f2bf(float f) {
    union { float f; unsigned u; } v; v.f = f;
    unsigned u = v.u;
    return (ushort)((u + 0x7FFFu + ((u >> 16) & 1u)) >> 16);
}

// ---------------- weight prepack: wt[kk][o][c] bf16, kk=ky*3+kx ----------------
// blockIdx.y: 0 -> w_hc, 1 -> w_hf. 73728 elements each.
__global__ __launch_bounds__(256) void k_packw(const float* __restrict__ whc,
                                               const float* __restrict__ whf,
                                               ushort* __restrict__ wt) {
    int idx = blockIdx.x * 256 + threadIdx.x;          // 0..73727
    const float* src = blockIdx.y ? whf : whc;
    ushort* dst = wt + (size_t)blockIdx.y * 73728;
    int kk = idx / 8192, rem = idx - kk * 8192;
    int o = rem >> 7, c = rem & 127;
    dst[(kk * 64 + o) * 128 + c] = f2bf(src[(size_t)(o * 128 + c) * 9 + kk]);
}

// ---------------- input prepack: xp[b][g=16][y1=46][x1=50][e=8] bf16, zero borders ----------------
// g<8: rgb channels g*8+e ; g>=8: depth channels (g-8)*8+e. y1=y+1, x1=x+1.
__global__ __launch_bounds__(256) void k_packin(const float* __restrict__ rgb,
                                                const float* __restrict__ depth,
                                                ushort* __restrict__ xp) {
    const int g = blockIdx.x, b = blockIdx.y, t = threadIdx.x;
    const float* base = (g < 8) ? rgb + ((size_t)b*64 + g*8)*P_
                                : depth + ((size_t)b*64 + (g-8)*8)*P_;
    ushort* dst = xp + ((size_t)(b*16 + g))*46*50*8;
    for (int pos = t; pos < 46*50; pos += 256) {
        int y1 = pos / 50, x1 = pos - y1*50;
        uint4 val = {0u,0u,0u,0u};
        if (y1 >= 1 && y1 <= 44 && x1 >= 1 && x1 <= 44) {
            const float* s = base + (y1-1)*44 + (x1-1);
            ushort h[8];
            #pragma unroll
            for (int e = 0; e < 8; ++e) h[e] = f2bf(s[(size_t)e*P_]);
            val.x = h[0] | ((unsigned)h[1] << 16);
            val.y = h[2] | ((unsigned)h[3] << 16);
            val.z = h[4] | ((unsigned)h[5] << 16);
            val.w = h[6] | ((unsigned)h[7] << 16);
        }
        *(uint4*)(dst + (size_t)pos*8) = val;
    }
}

// ---------------- h_att prepack: groups 0-7 = hc*satt, 8-15 = hc*catt ----------------
__global__ __launch_bounds__(256) void k_packatt(const float* __restrict__ hc,
                                                 const float* __restrict__ satt,
                                                 const float* __restrict__ catt,
                                                 ushort* __restrict__ xp) {
    const int g = blockIdx.x, b = blockIdx.y, t = threadIdx.x;
    const int c0 = (g & 7) * 8;
    const float* base = hc + ((size_t)b*64 + c0)*P_;
    ushort* dst = xp + ((size_t)(b*16 + g))*46*50*8;
    const bool spat = (g < 8);
    float ca[8];
    #pragma unroll
    for (int e = 0; e < 8; ++e) ca[e] = catt[b*64 + c0 + e];
    for (int pos = t; pos < 46*50; pos += 256) {
        int y1 = pos / 50, x1 = pos - y1*50;
        uint4 val = {0u,0u,0u,0u};
        if (y1 >= 1 && y1 <= 44 && x1 >= 1 && x1 <= 44) {
            int pix = (y1-1)*44 + (x1-1);
            const float* s = base + pix;
            float sv = spat ? satt[(size_t)b*P_ + pix] : 0.f;
            ushort h[8];
            #pragma unroll
            for (int e = 0; e < 8; ++e) {
                float v = s[(size_t)e*P_] * (spat ? sv : ca[e]);
                h[e] = f2bf(v);
            }
            val.x = h[0] | ((unsigned)h[1] << 16);
            val.y = h[2] | ((unsigned)h[3] << 16);
            val.z = h[4] | ((unsigned)h[5] << 16);
            val.w = h[6] | ((unsigned)h[7] << 16);
        }
        *(uint4*)(dst + (size_t)pos*8) = val;
    }
}

// ---------------- MFMA conv 3x3 pad=1: 128ch -> 64ch, relu(.+bias) ----------------
// grid (11 row-tiles of 4, 16 b), block 256 = 4 waves. Wave w -> output row r0+w.
// Per wave: M=64 (4 frags) x N=48 (3 frags, x>=44 masked). K: 4 slices of 32 ch.
__global__ __launch_bounds__(256) void k_conv_mfma(const ushort* __restrict__ xp,
                                                   const ushort* __restrict__ wt,
                                                   const float* __restrict__ bias,
                                                   float* __restrict__ out) {
    __shared__ ushort lds[9600];   // [cg=4][row=6][x=50][e=8]
    const int rt = blockIdx.x, b = blockIdx.y, t = threadIdx.x;
    const int w = t >> 6, lane = t & 63, lr = lane & 15, lg = lane >> 4;
    const int r0 = rt * 4;
    f32x4 acc[4][3];
    #pragma unroll
    for (int mf = 0; mf < 4; ++mf)
        #pragma unroll
        for (int nf = 0; nf < 3; ++nf)
            acc[mf][nf] = (f32x4){0.f, 0.f, 0.f, 0.f};

    for (int s = 0; s < 4; ++s) {
        __syncthreads();
        const ushort* gsrc = xp + ((size_t)(b*16 + s*4))*46*50*8;
        for (int u = t; u < 1200; u += 256) {
            int cg = u / 300, rem = u - cg*300;
            int rr = rem / 50, xx = rem - rr*50;
            uint4 v = *(const uint4*)(gsrc + (((size_t)cg*46 + (r0+rr))*50 + xx)*8);
            *(uint4*)(lds + (size_t)u*8) = v;
        }
        __syncthreads();
        const int abase = s*32 + lg*8;
        #pragma unroll
        for (int kk = 0; kk < 9; ++kk) {
            bf16x8 af[4];
            #pragma unroll
            for (int mf = 0; mf < 4; ++mf)
                af[mf] = *(const bf16x8*)(wt + (size_t)(kk*64 + mf*16 + lr)*128 + abase);
            const int ky = kk / 3, kx = kk - ky*3;
            #pragma unroll
            for (int nf = 0; nf < 3; ++nf) {
                bf16x8 bf = *(const bf16x8*)&lds[((lg*6 + (w + ky))*50 + (nf*16 + lr + kx))*8];
                #pragma unroll
                for (int mf = 0; mf < 4; ++mf)
                    acc[mf][nf] = __builtin_amdgcn_mfma_f32_16x16x32_bf16(af[mf], bf, acc[mf][nf], 0, 0, 0);
            }
        }
    }
    const int y = r0 + w;
    #pragma unroll
    for (int nf = 0; nf < 3; ++nf) {
        int x = nf*16 + lr;
        if (x < 44) {
            #pragma unroll
            for (int mf = 0; mf < 4; ++mf) {
                #pragma unroll
                for (int i = 0; i < 4; ++i) {
                    int o = mf*16 + lg*4 + i;
                    out[(((size_t)b*64 + o)*44 + y)*44 + x] = fmaxf(acc[mf][nf][i] + bias[o], 0.f);
                }
            }
        }
    }
}

// ---------------- depth transpose: dT[b][p][c] = depth[b][c][p] ----------------
__global__ __launch_bounds__(256) void k_tdepth(const float* __restrict__ depth,
                                                float* __restrict__ dT) {
    __shared__ float buf[64][65];
    const int b = blockIdx.y;
    const int p0 = blockIdx.x * 64;
    const int t = threadIdx.x;
    {
        const int pl = t & 63;
        const int cg = (t >> 6) * 16;
        #pragma unroll
        for (int i = 0; i < 16; ++i) {
            int c = cg + i;
            int p = p0 + pl;
            buf[c][pl] = (p < P_) ? depth[((size_t)b*64 + c)*P_ + p] : 0.f;
        }
    }
    __syncthreads();
    {
        const int cc = t & 63;
        const int pg = (t >> 6) * 16;
        #pragma unroll
        for (int i = 0; i < 16; ++i) {
            int p = p0 + pg + i;
            if (p < P_) dT[((size_t)b*P_ + p)*64 + cc] = buf[cc][pg + i];
        }
    }
}

// ---------------- depth_corr[b][c] = sum_hw rgb*depth ----------------
__global__ __launch_bounds__(64) void k_dcorr(const float* __restrict__ rgb,
                                              const float* __restrict__ depth,
                                              float* __restrict__ dcorr) {
    const int c = blockIdx.x, b = blockIdx.y, lane = threadIdx.x;
    const float* r = rgb + ((size_t)b*64 + c)*P_;
    const float* d = depth + ((size_t)b*64 + c)*P_;
    float acc = 0.f;
    for (int p = lane; p < P_; p += 64) acc = fmaf(r[p], d[p], acc);
    #pragma unroll
    for (int off = 32; off > 0; off >>= 1) acc += __shfl_down(acc, off, 64);
    if (lane == 0) dcorr[b*64 + c] = acc;
}

// ---------------- channel attention MLP: catt = sigmoid(2*mlp(dcorr)) ----------------
__global__ __launch_bounds__(64) void k_mlp(const float* __restrict__ dcorr,
                                            const float* __restrict__ wl1,
                                            const float* __restrict__ bl1,
                                            const float* __restrict__ wl2,
                                            const float* __restrict__ bl2,
                                            float* __restrict__ catt) {
    __shared__ float dc[64], h[16];
    const int b = blockIdx.x, t = threadIdx.x;
    dc[t] = dcorr[b*64 + t];
    __syncthreads();
    if (t < 16) {
        float a = bl1[t];
        #pragma unroll 8
        for (int c = 0; c < 64; ++c) a = fmaf(dc[c], wl1[t*64 + c], a);
        h[t] = fmaxf(a, 0.f);
    }
    __syncthreads();
    float m = bl2[t];
    #pragma unroll
    for (int j = 0; j < 16; ++j) m = fmaf(h[j], wl2[t*16 + j], m);
    catt[b*64 + t] = 1.f / (1.f + expf(-2.f*m));
}

// ---------------- U[b][o][kk][c] = sum_p w_s1[o][p][kk] * depth[b][c][p] ----------------
__global__ __launch_bounds__(256) void k_U(const float* __restrict__ dT,
                                           const float* __restrict__ ws1,
                                           float* __restrict__ U) {
    __shared__ float red[4*9*64];
    const int o = blockIdx.x, b = blockIdx.y;
    const int t = threadIdx.x, lane = t & 63, qw = t >> 6;
    float acc[9];
    #pragma unroll
    for (int k = 0; k < 9; ++k) acc[k] = 0.f;
    const float* dp = dT + (size_t)b*P_*64 + lane;
    const float* wbase = ws1 + (size_t)o*P_*9;
    const int p0 = qw*484, p1 = p0 + 484;
    #pragma unroll 4
    for (int p = p0; p < p1; ++p) {
        float d = dp[(size_t)p*64];
        const float* wp = wbase + (size_t)p*9;
        #pragma unroll
        for (int k = 0; k < 9; ++k) acc[k] = fmaf(d, wp[k], acc[k]);
    }
    #pragma unroll
    for (int k = 0; k < 9; ++k) red[(qw*9 + k)*64 + lane] = acc[k];
    __syncthreads();
    for (int s = t; s < 576; s += 256) {
        int kk = s >> 6, c = s & 63;
        float v = red[kk*64 + c] + red[(9+kk)*64 + c] + red[(18+kk)*64 + c] + red[(27+kk)*64 + c];
        U[(((size_t)b*32 + o)*9 + kk)*64 + c] = v;
    }
}

// ---------------- conv1: z1 = conv3x3_valid(pixel_corr, w_s1) via per-batch weights U ----------------
__global__ __launch_bounds__(256) void k_conv1(const float* __restrict__ rgb,
                                               const float* __restrict__ U,
                                               const float* __restrict__ bs1,
                                               float* __restrict__ z1) {
    __shared__ float tile[23*44];
    const int half = blockIdx.x, og = blockIdx.y, b = blockIdx.z;
    const int r0 = half * 21;
    const int t = threadIdx.x;
    float acc[4][4];
    #pragma unroll
    for (int oo = 0; oo < 4; ++oo)
        #pragma unroll
        for (int s = 0; s < 4; ++s) acc[oo][s] = 0.f;

    for (int c = 0; c < 64; ++c) {
        const float* src = rgb + ((size_t)b*64 + c)*P_ + r0*44;
        __syncthreads();
        for (int idx = t; idx < 23*44; idx += 256) tile[idx] = src[idx];
        __syncthreads();
        float wv[4][9];
        #pragma unroll
        for (int oo = 0; oo < 4; ++oo) {
            const float* up = U + (((size_t)b*32 + og*4 + oo)*9)*64 + c;
            #pragma unroll
            for (int k = 0; k < 9; ++k) wv[oo][k] = up[k*64];
        }
        #pragma unroll
        for (int s = 0; s < 4; ++s) {
            int px = t + s*256;
            if (px < 882) {
                int row = px / 42, col = px - row*42;
                float nb[9];
                #pragma unroll
                for (int ky = 0; ky < 3; ++ky)
                    #pragma unroll
                    for (int kx = 0; kx < 3; ++kx)
                        nb[ky*3+kx] = tile[(row+ky)*44 + col + kx];
                #pragma unroll
                for (int oo = 0; oo < 4; ++oo) {
                    float a = acc[oo][s];
                    #pragma unroll
                    for (int k = 0; k < 9; ++k) a = fmaf(nb[k], wv[oo][k], a);
                    acc[oo][s] = a;
                }
            }
        }
    }
    #pragma unroll
    for (int s = 0; s < 4; ++s) {
        int px = t + s*256;
        if (px < 882) {
            int row = px / 42, col = px - row*42;
            #pragma unroll
            for (int oo = 0; oo < 4; ++oo) {
                int o = og*4 + oo;
                z1[(((size_t)b*32 + o)*42 + (r0+row))*42 + col] = acc[oo][s] + bs1[o];
            }
        }
    }
}

// ---------------- BN stats ----------------
__global__ __launch_bounds__(256) void k_stats(const float* __restrict__ z, int npix,
                                               float* __restrict__ stats) {
    __shared__ float s1[256], s2[256];
    const int ch = blockIdx.x, t = threadIdx.x;
    float sum = 0.f, sq = 0.f;
    for (int b = 0; b < 16; ++b) {
        const float* p = z + ((size_t)b*32 + ch)*npix;
        for (int i = t; i < npix; i += 256) {
            float v = p[i];
            sum += v; sq = fmaf(v, v, sq);
        }
    }
    s1[t] = sum; s2[t] = sq;
    __syncthreads();
    for (int off = 128; off > 0; off >>= 1) {
        if (t < off) { s1[t] += s1[t+off]; s2[t] += s2[t+off]; }
        __syncthreads();
    }
    if (t == 0) { stats[ch*2] = s1[0]; stats[ch*2+1] = s2[0]; }
}

__device__ __forceinline__ void bn_coef(const float* stats, const float* g,
                                        const float* be, int ch, float inv_n,
                                        float& sc, float& sh) {
    float sum = stats[ch*2], sq = stats[ch*2+1];
    float mu = sum * inv_n;
    float var = sq * inv_n - mu*mu;
    float r = rsqrtf(var + EPS_);
    sc = g[ch] * r;
    sh = be[ch] - mu * sc;
}

// ---------------- conv2: 42->40, input = relu(bn1(z1)) ----------------
__global__ __launch_bounds__(256) void k_conv2(const float* __restrict__ z1,
                                               const float* __restrict__ ws2,
                                               const float* __restrict__ bs2,
                                               const float* __restrict__ g,
                                               const float* __restrict__ be,
                                               const float* __restrict__ stats,
                                               float* __restrict__ z2) {
    __shared__ float tile[22*42];
    const int half = blockIdx.x, og = blockIdx.y, b = blockIdx.z;
    const int r0 = half * 20;
    const int t = threadIdx.x;
    const float inv_n = 1.f / 28224.f;
    float acc[4][4];
    #pragma unroll
    for (int oo = 0; oo < 4; ++oo)
        #pragma unroll
        for (int s = 0; s < 4; ++s) acc[oo][s] = 0.f;

    for (int c = 0; c < 32; ++c) {
        float sc, sh;
        bn_coef(stats, g, be, c, inv_n, sc, sh);
        const float* src = z1 + ((size_t)b*32 + c)*1764 + r0*42;
        __syncthreads();
        for (int idx = t; idx < 22*42; idx += 256)
            tile[idx] = fmaxf(fmaf(src[idx], sc, sh), 0.f);
        __syncthreads();
        float wv[4][9];
        #pragma unroll
        for (int oo = 0; oo < 4; ++oo) {
            const float* wp = ws2 + ((size_t)(og*4 + oo)*32 + c)*9;
            #pragma unroll
            for (int k = 0; k < 9; ++k) wv[oo][k] = wp[k];
        }
        #pragma unroll
        for (int s = 0; s < 4; ++s) {
            int px = t + s*256;
            if (px < 800) {
                int row = px / 40, col = px - row*40;
                float nb[9];
                #pragma unroll
                for (int ky = 0; ky < 3; ++ky)
                    #pragma unroll
                    for (int kx = 0; kx < 3; ++kx)
                        nb[ky*3+kx] = tile[(row+ky)*42 + col + kx];
                #pragma unroll
                for (int oo = 0; oo < 4; ++oo) {
                    float a = acc[oo][s];
                    #pragma unroll
                    for (int k = 0; k < 9; ++k) a = fmaf(nb[k], wv[oo][k], a);
                    acc[oo][s] = a;
                }
            }
        }
    }
    #pragma unroll
    for (int s = 0; s < 4; ++s) {
        int px = t + s*256;
        if (px < 800) {
            int row = px / 40, col = px - row*40;
            #pragma unroll
            for (int oo = 0; oo < 4; ++oo) {
                int o = og*4 + oo;
                z2[(((size_t)b*32 + o)*40 + (r0+row))*40 + col] = acc[oo][s] + bs2[o];
            }
        }
    }
}

// ---------------- convT1: 40->42, input = relu(bn2(z2)) ----------------
__global__ __launch_bounds__(256) void k_dconv1(const float* __restrict__ z2,
                                                const float* __restrict__ wd1,
                                                const float* __restrict__ bd1,
                                                const float* __restrict__ g,
                                                const float* __restrict__ be,
                                                const float* __restrict__ stats,
                                                float* __restrict__ z3) {
    __shared__ float tile[23*44];
    const int half = blockIdx.x, og = blockIdx.y, b = blockIdx.z;
    const int r0 = half * 21;
    const int t = threadIdx.x;
    const float inv_n = 1.f / 25600.f;
    float acc[4][4];
    #pragma unroll
    for (int oo = 0; oo < 4; ++oo)
        #pragma unroll
        for (int s = 0; s < 4; ++s) acc[oo][s] = 0.f;

    for (int c = 0; c < 32; ++c) {
        float sc, sh;
        bn_coef(stats, g, be, c, inv_n, sc, sh);
        const float* src = z2 + ((size_t)b*32 + c)*1600;
        __syncthreads();
        for (int idx = t; idx < 23*44; idx += 256) {
            int ly = idx / 44, lx = idx - ly*44;
            int gy = r0 - 2 + ly, gx = lx - 2;
            float v = 0.f;
            if (gy >= 0 && gy < 40 && gx >= 0 && gx < 40)
                v = fmaxf(fmaf(src[gy*40 + gx], sc, sh), 0.f);
            tile[idx] = v;
        }
        __syncthreads();
        float wv[4][9];
        #pragma unroll
        for (int oo = 0; oo < 4; ++oo) {
            const float* wp = wd1 + ((size_t)c*32 + og*4 + oo)*9;
            #pragma unroll
            for (int m = 0; m < 9; ++m) wv[oo][m] = wp[m];
        }
        #pragma unroll
        for (int s = 0; s < 4; ++s) {
            int px = t + s*256;
            if (px < 882) {
                int row = px / 42, col = px - row*42;
                float nb[9];
                #pragma unroll
                for (int u = 0; u < 3; ++u)
                    #pragma unroll
                    for (int v = 0; v < 3; ++v)
                        nb[u*3+v] = tile[(row + 2 - u)*44 + (col + 2 - v)];
                #pragma unroll
                for (int oo = 0; oo < 4; ++oo) {
                    float a = acc[oo][s];
                    #pragma unroll
                    for (int m = 0; m < 9; ++m) a = fmaf(nb[m], wv[oo][m], a);
                    acc[oo][s] = a;
                }
            }
        }
    }
    #pragma unroll
    for (int s = 0; s < 4; ++s) {
        int px = t + s*256;
        if (px < 882) {
            int row = px / 42, col = px - row*42;
            #pragma unroll
            for (int oo = 0; oo < 4; ++oo) {
                int o = og*4 + oo;
                z3[(((size_t)b*32 + o)*42 + (r0+row))*42 + col] = acc[oo][s] + bd1[o];
            }
        }
    }
}

// ---------------- convT2: 42->44, sigmoid, 1 out channel ----------------
__global__ __launch_bounds__(256) void k_dconv2(const float* __restrict__ z3,
                                                const float* __restrict__ wd2,
                                                const float* __restrict__ bd2,
                                                const float* __restrict__ g,
                                                const float* __restrict__ be,
                                                const float* __restrict__ stats,
                                                float* __restrict__ satt) {
    __shared__ float tile[24*46];
    const int half = blockIdx.x, b = blockIdx.y;
    const int r0 = half * 22;
    const int t = threadIdx.x;
    const float inv_n = 1.f / 28224.f;
    float acc[4] = {0.f, 0.f, 0.f, 0.f};

    for (int c = 0; c < 32; ++c) {
        float sc, sh;
        bn_coef(stats, g, be, c, inv_n, sc, sh);
        const float* src = z3 + ((size_t)b*32 + c)*1764;
        __syncthreads();
        for (int idx = t; idx < 24*46; idx += 256) {
            int ly = idx / 46, lx = idx - ly*46;
            int gy = r0 - 2 + ly, gx = lx - 2;
            float v = 0.f;
            if (gy >= 0 && gy < 42 && gx >= 0 && gx < 42)
                v = fmaxf(fmaf(src[gy*42 + gx], sc, sh), 0.f);
            tile[idx] = v;
        }
        __syncthreads();
        float w9[9];
        #pragma unroll
        for (int m = 0; m < 9; ++m) w9[m] = wd2[c*9 + m];
        #pragma unroll
        for (int s = 0; s < 4; ++s) {
            int px = t + s*256;
            if (px < 968) {
                int row = px / 44, col = px - row*44;
                float a = acc[s];
                #pragma unroll
                for (int u = 0; u < 3; ++u)
                    #pragma unroll
                    for (int v = 0; v < 3; ++v)
                        a = fmaf(tile[(row + 2 - u)*46 + (col + 2 - v)], w9[u*3+v], a);
                acc[s] = a;
            }
        }
    }
    const float bb = bd2[0];
    #pragma unroll
    for (int s = 0; s < 4; ++s) {
        int px = t + s*256;
        if (px < 968) {
            int row = px / 44, col = px - row*44;
            float v = acc[s] + bb;
            satt[(size_t)b*P_ + (r0+row)*44 + col] = 1.f / (1.f + expf(-v));
        }
    }
}

extern "C" void kernel_launch(void* const* d_in, const int* in_sizes, int n_in,
                              void* d_out, int out_size, void* d_ws, size_t ws_size,
                              hipStream_t stream) {
    const float* depth = (const float*)d_in[0];
    const float* rgb   = (const float*)d_in[1];
    const float* w_hc  = (const float*)d_in[2];
    const float* b_hc  = (const float*)d_in[3];
    const float* w_hf  = (const float*)d_in[4];
    const float* b_hf  = (const float*)d_in[5];
    const float* w_s1  = (const float*)d_in[6];
    const float* bs1   = (const float*)d_in[7];
    const float* g1    = (const float*)d_in[8];
    const float* be1   = (const float*)d_in[9];
    const float* w_s2  = (const float*)d_in[10];
    const float* bs2   = (const float*)d_in[11];
    const float* g2    = (const float*)d_in[12];
    const float* be2   = (const float*)d_in[13];
    const float* w_d1  = (const float*)d_in[14];
    const float* bd1   = (const float*)d_in[15];
    const float* g3    = (const float*)d_in[16];
    const float* be3   = (const float*)d_in[17];
    const float* w_d2  = (const float*)d_in[18];
    const float* bd2   = (const float*)d_in[19];
    const float* w_l1  = (const float*)d_in[20];
    const float* bl1   = (const float*)d_in[21];
    const float* w_l2  = (const float*)d_in[22];
    const float* bl2   = (const float*)d_in[23];

    float* out = (float*)d_out;
    float* ws  = (float*)d_ws;

    float* hc    = ws;                    // 1,982,464
    float* dT    = hc   + 1982464;        // 1,982,464 (later reused by z1,z2)
    float* z1    = dT;                    // alias: 903,168 (after k_U done)
    float* z2    = dT   + 903168;         // 819,200
    float* z3    = dT   + 1982464;        // 903,168
    float* U     = z3   + 903168;         // 294,912
    float* satt  = U    + 294912;         // 30,976
    float* catt  = satt + 30976;          // 1,024
    float* dcor  = catt + 1024;           // 1,024
    float* stats = dcor + 1024;           // 192
    ushort* wpck = (ushort*)(stats + 192);          // 2*73728 ushort
    ushort* xpck = wpck + 147456;                    // 16*16*46*50*8 ushort

    k_packw<<<dim3(288,2), 256, 0, stream>>>(w_hc, w_hf, wpck);
    k_packin<<<dim3(16,16), 256, 0, stream>>>(rgb, depth, xpck);
    k_conv_mfma<<<dim3(11,16), 256, 0, stream>>>(xpck, wpck, b_hc, hc);

    k_tdepth<<<dim3(31,16), 256, 0, stream>>>(depth, dT);
    k_dcorr<<<dim3(64,16), 64, 0, stream>>>(rgb, depth, dcor);
    k_mlp<<<16, 64, 0, stream>>>(dcor, w_l1, bl1, w_l2, bl2, catt);
    k_U<<<dim3(32,16), 256, 0, stream>>>(dT, w_s1, U);
    k_conv1<<<dim3(2,8,16), 256, 0, stream>>>(rgb, U, bs1, z1);
    k_stats<<<32, 256, 0, stream>>>(z1, 1764, stats);
    k_conv2<<<dim3(2,8,16), 256, 0, stream>>>(z1, w_s2, bs2, g1, be1, stats, z2);
    k_stats<<<32, 256, 0, stream>>>(z2, 1600, stats + 64);
    k_dconv1<<<dim3(2,8,16), 256, 0, stream>>>(z2, w_d1, bd1, g2, be2, stats + 64, z3);
    k_stats<<<32, 256, 0, stream>>>(z3, 1764, stats + 128);
    k_dconv2<<<dim3(2,16), 256, 0, stream>>>(z3, w_d2, bd2, g3, be3, stats + 128, satt);

    k_packatt<<<dim3(16,16), 256, 0, stream>>>(hc, satt, catt, xpck);
    k_conv_mfma<<<dim3(11,16), 256, 0, stream>>>(xpck, wpck + 73728, b_hf, out);
}

// Round 4
// 260.900 us; speedup vs baseline: 3.5545x; 2.2478x over previous
//
#include <hip/hip_runtime.h>
#include <math.h>

#define P_ 1936   // 44*44
#define EPS_ 1e-5f

typedef __attribute__((ext_vector_type(8))) short bf16x8;
typedef __attribute__((ext_vector_type(4))) float f32x4;
typedef __attribute__((ext_vector_type(4))) ushort u16x4;

__device__ __forceinline__ ushort f2bf(float f) {
    union { float f; unsigned u; } v; v.f = f;
    unsigned u = v.u;
    return (ushort)((u + 0x7FFFu + ((u >> 16) & 1u)) >> 16);
}
__device__ __forceinline__ float bf2f(ushort h) {
    union { unsigned u; float f; } v; v.u = (unsigned)h << 16;
    return v.f;
}

__device__ __forceinline__ void bn_coef(const float* stats, const float* g,
                                        const float* be, int ch, float inv_n,
                                        float& sc, float& sh) {
    float sum = stats[ch*2], sq = stats[ch*2+1];
    float mu = sum * inv_n;
    float var = sq * inv_n - mu*mu;
    float r = rsqrtf(var + EPS_);
    sc = g[ch] * r;
    sh = be[ch] - mu * sc;
}

// ---------------- weight prepack: wt[kk][o][c] bf16 (128-ch convs) ----------------
__global__ __launch_bounds__(256) void k_packw(const float* __restrict__ whc,
                                               const float* __restrict__ whf,
                                               ushort* __restrict__ wt) {
    int idx = blockIdx.x * 256 + threadIdx.x;          // 0..73727
    const float* src = blockIdx.y ? whf : whc;
    ushort* dst = wt + (size_t)blockIdx.y * 73728;
    int kk = idx / 8192, rem = idx - kk * 8192;
    int o = rem >> 7, c = rem & 127;
    dst[(kk * 64 + o) * 128 + c] = f2bf(src[(size_t)(o * 128 + c) * 9 + kk]);
}

// ---------------- small weight prepack: ws2 and wd1(flipped) -> [kk][o=32][c=32] ----------------
__global__ __launch_bounds__(256) void k_packw2(const float* __restrict__ ws2,
                                                const float* __restrict__ wd1,
                                                ushort* __restrict__ a2,
                                                ushort* __restrict__ a3) {
    int idx = blockIdx.x * 256 + threadIdx.x;          // 0..9215
    if (idx >= 9216) return;
    int kk = idx >> 10, rem = idx & 1023, o = rem >> 5, c = rem & 31;
    a2[idx] = f2bf(ws2[((size_t)o*32 + c)*9 + kk]);
    a3[idx] = f2bf(wd1[((size_t)c*32 + o)*9 + (8 - kk)]);
}

// ---------------- input prepack: xp[b][g=16][46][50][8] bf16, zero borders ----------------
__global__ __launch_bounds__(256) void k_packin(const float* __restrict__ rgb,
                                                const float* __restrict__ depth,
                                                ushort* __restrict__ xp) {
    const int g = blockIdx.x, b = blockIdx.y, t = threadIdx.x;
    const float* base = (g < 8) ? rgb + ((size_t)b*64 + g*8)*P_
                                : depth + ((size_t)b*64 + (g-8)*8)*P_;
    ushort* dst = xp + ((size_t)(b*16 + g))*46*50*8;
    for (int pos = t; pos < 46*50; pos += 256) {
        int y1 = pos / 50, x1 = pos - y1*50;
        uint4 val = {0u,0u,0u,0u};
        if (y1 >= 1 && y1 <= 44 && x1 >= 1 && x1 <= 44) {
            const float* s = base + (y1-1)*44 + (x1-1);
            ushort h[8];
            #pragma unroll
            for (int e = 0; e < 8; ++e) h[e] = f2bf(s[(size_t)e*P_]);
            val.x = h[0] | ((unsigned)h[1] << 16);
            val.y = h[2] | ((unsigned)h[3] << 16);
            val.z = h[4] | ((unsigned)h[5] << 16);
            val.w = h[6] | ((unsigned)h[7] << 16);
        }
        *(uint4*)(dst + (size_t)pos*8) = val;
    }
}

// ---------------- h_att prepack ----------------
__global__ __launch_bounds__(256) void k_packatt(const float* __restrict__ hc,
                                                 const float* __restrict__ satt,
                                                 const float* __restrict__ catt,
                                                 ushort* __restrict__ xp) {
    const int g = blockIdx.x, b = blockIdx.y, t = threadIdx.x;
    const int c0 = (g & 7) * 8;
    const float* base = hc + ((size_t)b*64 + c0)*P_;
    ushort* dst = xp + ((size_t)(b*16 + g))*46*50*8;
    const bool spat = (g < 8);
    float ca[8];
    #pragma unroll
    for (int e = 0; e < 8; ++e) ca[e] = catt[b*64 + c0 + e];
    for (int pos = t; pos < 46*50; pos += 256) {
        int y1 = pos / 50, x1 = pos - y1*50;
        uint4 val = {0u,0u,0u,0u};
        if (y1 >= 1 && y1 <= 44 && x1 >= 1 && x1 <= 44) {
            int pix = (y1-1)*44 + (x1-1);
            const float* s = base + pix;
            float sv = spat ? satt[(size_t)b*P_ + pix] : 0.f;
            ushort h[8];
            #pragma unroll
            for (int e = 0; e < 8; ++e) {
                float v = s[(size_t)e*P_] * (spat ? sv : ca[e]);
                h[e] = f2bf(v);
            }
            val.x = h[0] | ((unsigned)h[1] << 16);
            val.y = h[2] | ((unsigned)h[3] << 16);
            val.z = h[4] | ((unsigned)h[5] << 16);
            val.w = h[6] | ((unsigned)h[7] << 16);
        }
        *(uint4*)(dst + (size_t)pos*8) = val;
    }
}

// ---------------- MFMA conv 3x3 pad=1: 128ch -> 64ch, relu(.+bias), f32 out ----------------
__global__ __launch_bounds__(256) void k_conv_mfma(const ushort* __restrict__ xp,
                                                   const ushort* __restrict__ wt,
                                                   const float* __restrict__ bias,
                                                   float* __restrict__ out) {
    __shared__ ushort lds[9616];   // [cg=4][row=6][x=50][8] + slack
    const int rt = blockIdx.x, b = blockIdx.y, t = threadIdx.x;
    const int w = t >> 6, lane = t & 63, lr = lane & 15, lg = lane >> 4;
    const int r0 = rt * 4;
    f32x4 acc[4][3];
    #pragma unroll
    for (int mf = 0; mf < 4; ++mf)
        #pragma unroll
        for (int nf = 0; nf < 3; ++nf)
            acc[mf][nf] = (f32x4){0.f, 0.f, 0.f, 0.f};

    for (int s = 0; s < 4; ++s) {
        __syncthreads();
        const ushort* gsrc = xp + ((size_t)(b*16 + s*4))*46*50*8;
        for (int u = t; u < 1200; u += 256) {
            int cg = u / 300, rem = u - cg*300;
            int rr = rem / 50, xx = rem - rr*50;
            uint4 v = *(const uint4*)(gsrc + (((size_t)cg*46 + (r0+rr))*50 + xx)*8);
            *(uint4*)(lds + (size_t)u*8) = v;
        }
        __syncthreads();
        const int abase = s*32 + lg*8;
        #pragma unroll
        for (int kk = 0; kk < 9; ++kk) {
            bf16x8 af[4];
            #pragma unroll
            for (int mf = 0; mf < 4; ++mf)
                af[mf] = *(const bf16x8*)(wt + (size_t)(kk*64 + mf*16 + lr)*128 + abase);
            const int ky = kk / 3, kx = kk - ky*3;
            #pragma unroll
            for (int nf = 0; nf < 3; ++nf) {
                bf16x8 bf = *(const bf16x8*)&lds[((lg*6 + (w + ky))*50 + (nf*16 + lr + kx))*8];
                #pragma unroll
                for (int mf = 0; mf < 4; ++mf)
                    acc[mf][nf] = __builtin_amdgcn_mfma_f32_16x16x32_bf16(af[mf], bf, acc[mf][nf], 0, 0, 0);
            }
        }
    }
    const int y = r0 + w;
    #pragma unroll
    for (int nf = 0; nf < 3; ++nf) {
        int x = nf*16 + lr;
        if (x < 44) {
            #pragma unroll
            for (int mf = 0; mf < 4; ++mf) {
                #pragma unroll
                for (int i = 0; i < 4; ++i) {
                    int o = mf*16 + lg*4 + i;
                    out[(((size_t)b*64 + o)*44 + y)*44 + x] = fmaxf(acc[mf][nf][i] + bias[o], 0.f);
                }
            }
        }
    }
}

// ---------------- depth transpose ----------------
__global__ __launch_bounds__(256) void k_tdepth(const float* __restrict__ depth,
                                                float* __restrict__ dT) {
    __shared__ float buf[64][65];
    const int b = blockIdx.y;
    const int p0 = blockIdx.x * 64;
    const int t = threadIdx.x;
    {
        const int pl = t & 63;
        const int cg = (t >> 6) * 16;
        #pragma unroll
        for (int i = 0; i < 16; ++i) {
            int c = cg + i;
            int p = p0 + pl;
            buf[c][pl] = (p < P_) ? depth[((size_t)b*64 + c)*P_ + p] : 0.f;
        }
    }
    __syncthreads();
    {
        const int cc = t & 63;
        const int pg = (t >> 6) * 16;
        #pragma unroll
        for (int i = 0; i < 16; ++i) {
            int p = p0 + pg + i;
            if (p < P_) dT[((size_t)b*P_ + p)*64 + cc] = buf[cc][pg + i];
        }
    }
}

// ---------------- depth_corr ----------------
__global__ __launch_bounds__(64) void k_dcorr(const float* __restrict__ rgb,
                                              const float* __restrict__ depth,
                                              float* __restrict__ dcorr) {
    const int c = blockIdx.x, b = blockIdx.y, lane = threadIdx.x;
    const float* r = rgb + ((size_t)b*64 + c)*P_;
    const float* d = depth + ((size_t)b*64 + c)*P_;
    float acc = 0.f;
    for (int p = lane; p < P_; p += 64) acc = fmaf(r[p], d[p], acc);
    #pragma unroll
    for (int off = 32; off > 0; off >>= 1) acc += __shfl_down(acc, off, 64);
    if (lane == 0) dcorr[b*64 + c] = acc;
}

// ---------------- channel attention MLP ----------------
__global__ __launch_bounds__(64) void k_mlp(const float* __restrict__ dcorr,
                                            const float* __restrict__ wl1,
                                            const float* __restrict__ bl1,
                                            const float* __restrict__ wl2,
                                            const float* __restrict__ bl2,
                                            float* __restrict__ catt) {
    __shared__ float dc[64], h[16];
    const int b = blockIdx.x, t = threadIdx.x;
    dc[t] = dcorr[b*64 + t];
    __syncthreads();
    if (t < 16) {
        float a = bl1[t];
        #pragma unroll 8
        for (int c = 0; c < 64; ++c) a = fmaf(dc[c], wl1[t*64 + c], a);
        h[t] = fmaxf(a, 0.f);
    }
    __syncthreads();
    float m = bl2[t];
    #pragma unroll
    for (int j = 0; j < 16; ++j) m = fmaf(h[j], wl2[t*16 + j], m);
    catt[b*64 + t] = 1.f / (1.f + expf(-2.f*m));
}

// ---------------- U -> bf16 packed [b][kk][o=32][c=64] ----------------
__global__ __launch_bounds__(256) void k_U(const float* __restrict__ dT,
                                           const float* __restrict__ ws1,
                                           ushort* __restrict__ upck) {
    __shared__ float red[4*9*64];
    const int o = blockIdx.x, b = blockIdx.y;
    const int t = threadIdx.x, lane = t & 63, qw = t >> 6;
    float acc[9];
    #pragma unroll
    for (int k = 0; k < 9; ++k) acc[k] = 0.f;
    const float* dp = dT + (size_t)b*P_*64 + lane;
    const float* wbase = ws1 + (size_t)o*P_*9;
    const int p0 = qw*484, p1 = p0 + 484;
    #pragma unroll 4
    for (int p = p0; p < p1; ++p) {
        float d = dp[(size_t)p*64];
        const float* wp = wbase + (size_t)p*9;
        #pragma unroll
        for (int k = 0; k < 9; ++k) acc[k] = fmaf(d, wp[k], acc[k]);
    }
    #pragma unroll
    for (int k = 0; k < 9; ++k) red[(qw*9 + k)*64 + lane] = acc[k];
    __syncthreads();
    for (int s = t; s < 576; s += 256) {
        int kk = s >> 6, c = s & 63;
        float v = red[kk*64 + c] + red[(9+kk)*64 + c] + red[(18+kk)*64 + c] + red[(27+kk)*64 + c];
        upck[((size_t)(b*9 + kk)*32 + o)*64 + c] = f2bf(v);
    }
}

// ---------------- conv1 MFMA: rgb(64ch) x U -> z1p bf16 [b][cg4][42][48][8] + stats ----------------
__global__ __launch_bounds__(256) void k_conv1_mfma(const ushort* __restrict__ xp,
                                                    const ushort* __restrict__ upck,
                                                    const float* __restrict__ bs1,
                                                    ushort* __restrict__ z1p,
                                                    float* __restrict__ stats) {
    __shared__ ushort lds[8*6*50*8 + 32];
    __shared__ float ssum[32], ssq[32];
    const int rt = blockIdx.x, b = blockIdx.y, t = threadIdx.x;
    const int w = t >> 6, lane = t & 63, lr = lane & 15, lg = lane >> 4;
    const int r0 = rt * 4;
    if (t < 32) { ssum[t] = 0.f; ssq[t] = 0.f; }
    f32x4 acc[2][3];
    #pragma unroll
    for (int mf = 0; mf < 2; ++mf)
        #pragma unroll
        for (int nf = 0; nf < 3; ++nf)
            acc[mf][nf] = (f32x4){0.f, 0.f, 0.f, 0.f};

    const ushort* gsrc = xp + (size_t)b*16*46*50*8;   // rgb groups 0..7
    for (int u = t; u < 2400; u += 256) {
        int cg = u / 300, rem = u - cg*300;
        int rr = rem / 50, xx = rem - rr*50;
        int y1 = min(r0 + 1 + rr, 45);
        *(uint4*)(lds + (size_t)u*8) = *(const uint4*)(gsrc + (((size_t)cg*46 + y1)*50 + xx)*8);
    }
    __syncthreads();
    #pragma unroll
    for (int s = 0; s < 2; ++s) {
        #pragma unroll
        for (int kk = 0; kk < 9; ++kk) {
            bf16x8 af[2];
            #pragma unroll
            for (int mf = 0; mf < 2; ++mf)
                af[mf] = *(const bf16x8*)(upck + ((size_t)(b*9 + kk)*32 + mf*16 + lr)*64 + s*32 + lg*8);
            const int ky = kk / 3, kx = kk - ky*3;
            #pragma unroll
            for (int nf = 0; nf < 3; ++nf) {
                bf16x8 bv = *(const bf16x8*)&lds[(((s*4 + lg)*6 + (w + ky))*50 + (nf*16 + lr + kx + 1))*8];
                #pragma unroll
                for (int mf = 0; mf < 2; ++mf)
                    acc[mf][nf] = __builtin_amdgcn_mfma_f32_16x16x32_bf16(af[mf], bv, acc[mf][nf], 0, 0, 0);
            }
        }
    }
    const int y = r0 + w;
    const int cb = lg*4;
    if (y < 42) {
        float ls[2][4], lq[2][4], br[2][4];
        #pragma unroll
        for (int mf = 0; mf < 2; ++mf)
            #pragma unroll
            for (int i = 0; i < 4; ++i) {
                ls[mf][i] = 0.f; lq[mf][i] = 0.f;
                br[mf][i] = bs1[mf*16 + cb + i];
            }
        #pragma unroll
        for (int nf = 0; nf < 3; ++nf) {
            int x = nf*16 + lr;
            bool xv = (x < 42);
            #pragma unroll
            for (int mf = 0; mf < 2; ++mf) {
                u16x4 pk;
                #pragma unroll
                for (int i = 0; i < 4; ++i) {
                    float v = acc[mf][nf][i] + br[mf][i];
                    if (xv) { ls[mf][i] += v; lq[mf][i] = fmaf(v, v, lq[mf][i]); }
                    pk[i] = f2bf(v);
                }
                if (xv) {
                    int cg1 = mf*2 + (lg >> 1);
                    *(u16x4*)(z1p + ((((size_t)b*4 + cg1)*42 + y)*48 + x)*8 + (lg&1)*4) = pk;
                }
            }
        }
        #pragma unroll
        for (int mf = 0; mf < 2; ++mf)
            #pragma unroll
            for (int i = 0; i < 4; ++i) {
                float s0 = ls[mf][i], q0 = lq[mf][i];
                #pragma unroll
                for (int m = 1; m < 16; m <<= 1) { s0 += __shfl_xor(s0, m, 64); q0 += __shfl_xor(q0, m, 64); }
                if (lr == 0) { atomicAdd(&ssum[mf*16 + cb + i], s0); atomicAdd(&ssq[mf*16 + cb + i], q0); }
            }
    }
    __syncthreads();
    if (t < 32) { atomicAdd(&stats[t*2], ssum[t]); atomicAdd(&stats[t*2+1], ssq[t]); }
}

// ---------------- conv2 MFMA: relu(bn1(z1)) x ws2 -> z2p bf16 padded [b][cg4][46][48][8] + stats ----------------
__global__ __launch_bounds__(256) void k_conv2_mfma(const ushort* __restrict__ z1p,
                                                    const ushort* __restrict__ apck,
                                                    const float* __restrict__ bs2,
                                                    const float* __restrict__ g1,
                                                    const float* __restrict__ be1,
                                                    const float* __restrict__ statsIn,
                                                    ushort* __restrict__ z2p,
                                                    float* __restrict__ statsOut) {
    __shared__ ushort lds[4*6*48*8 + 32];
    __shared__ float sc[32], sh[32], ssum[32], ssq[32];
    const int rt = blockIdx.x, b = blockIdx.y, t = threadIdx.x;
    const int w = t >> 6, lane = t & 63, lr = lane & 15, lg = lane >> 4;
    const int r0 = rt * 4;
    if (t < 32) {
        bn_coef(statsIn, g1, be1, t, 1.f/28224.f, sc[t], sh[t]);
        ssum[t] = 0.f; ssq[t] = 0.f;
    }
    __syncthreads();
    f32x4 acc[2][3];
    #pragma unroll
    for (int mf = 0; mf < 2; ++mf)
        #pragma unroll
        for (int nf = 0; nf < 3; ++nf)
            acc[mf][nf] = (f32x4){0.f, 0.f, 0.f, 0.f};

    for (int u = t; u < 1152; u += 256) {
        int cg = u / 288, rem = u - cg*288;
        int rr = rem / 48, xx = rem - rr*48;
        uint4 raw = *(const uint4*)(z1p + ((((size_t)b*4 + cg)*42 + (r0 + rr))*48 + xx)*8);
        unsigned arr[4] = {raw.x, raw.y, raw.z, raw.w};
        ushort h[8];
        #pragma unroll
        for (int e = 0; e < 8; ++e) {
            ushort hv = (e & 1) ? (ushort)(arr[e>>1] >> 16) : (ushort)(arr[e>>1] & 0xffffu);
            float f = fmaxf(fmaf(bf2f(hv), sc[cg*8 + e], sh[cg*8 + e]), 0.f);
            h[e] = f2bf(f);
        }
        uint4 v;
        v.x = h[0] | ((unsigned)h[1] << 16);
        v.y = h[2] | ((unsigned)h[3] << 16);
        v.z = h[4] | ((unsigned)h[5] << 16);
        v.w = h[6] | ((unsigned)h[7] << 16);
        *(uint4*)(lds + (size_t)u*8) = v;
    }
    __syncthreads();
    #pragma unroll
    for (int kk = 0; kk < 9; ++kk) {
        bf16x8 af[2];
        #pragma unroll
        for (int mf = 0; mf < 2; ++mf)
            af[mf] = *(const bf16x8*)(apck + (size_t)(kk*32 + mf*16 + lr)*32 + lg*8);
        const int ky = kk / 3, kx = kk - ky*3;
        #pragma unroll
        for (int nf = 0; nf < 3; ++nf) {
            bf16x8 bv = *(const bf16x8*)&lds[((lg*6 + (w + ky))*48 + (nf*16 + lr + kx))*8];
            #pragma unroll
            for (int mf = 0; mf < 2; ++mf)
                acc[mf][nf] = __builtin_amdgcn_mfma_f32_16x16x32_bf16(af[mf], bv, acc[mf][nf], 0, 0, 0);
        }
    }
    const int y = r0 + w;   // 0..39, all valid
    const int cb = lg*4;
    {
        float ls[2][4], lq[2][4], br[2][4];
        #pragma unroll
        for (int mf = 0; mf < 2; ++mf)
            #pragma unroll
            for (int i = 0; i < 4; ++i) {
                ls[mf][i] = 0.f; lq[mf][i] = 0.f;
                br[mf][i] = bs2[mf*16 + cb + i];
            }
        #pragma unroll
        for (int nf = 0; nf < 3; ++nf) {
            int x = nf*16 + lr;
            bool xv = (x < 40);
            #pragma unroll
            for (int mf = 0; mf < 2; ++mf) {
                u16x4 pk;
                #pragma unroll
                for (int i = 0; i < 4; ++i) {
                    float v = acc[mf][nf][i] + br[mf][i];
                    if (xv) { ls[mf][i] += v; lq[mf][i] = fmaf(v, v, lq[mf][i]); }
                    pk[i] = f2bf(v);
                }
                if (xv) {
                    int cg1 = mf*2 + (lg >> 1);
                    *(u16x4*)(z2p + ((((size_t)b*4 + cg1)*46 + (y+2))*48 + (x+2))*8 + (lg&1)*4) = pk;
                }
            }
        }
        #pragma unroll
        for (int mf = 0; mf < 2; ++mf)
            #pragma unroll
            for (int i = 0; i < 4; ++i) {
                float s0 = ls[mf][i], q0 = lq[mf][i];
                #pragma unroll
                for (int m = 1; m < 16; m <<= 1) { s0 += __shfl_xor(s0, m, 64); q0 += __shfl_xor(q0, m, 64); }
                if (lr == 0) { atomicAdd(&ssum[mf*16 + cb + i], s0); atomicAdd(&ssq[mf*16 + cb + i], q0); }
            }
    }
    __syncthreads();
    if (t < 32) { atomicAdd(&statsOut[t*2], ssum[t]); atomicAdd(&statsOut[t*2+1], ssq[t]); }
}

// ---------------- dconv1 MFMA: relu(bn2(z2)) *T wd1 -> z3p bf16 padded [b][cg4][46][48][8] + stats ----------------
// FIX: bn+relu applied ONLY to valid z2 entries (padded rows/cols 2..41); padding stays 0.
__global__ __launch_bounds__(256) void k_dconv1_mfma(const ushort* __restrict__ z2p,
                                                     const ushort* __restrict__ apck,
                                                     const float* __restrict__ bd1,
                                                     const float* __restrict__ g2,
                                                     const float* __restrict__ be2,
                                                     const float* __restrict__ statsIn,
                                                     ushort* __restrict__ z3p,
                                                     float* __restrict__ statsOut) {
    __shared__ ushort lds[4*6*48*8 + 32];
    __shared__ float sc[32], sh[32], ssum[32], ssq[32];
    const int rt = blockIdx.x, b = blockIdx.y, t = threadIdx.x;
    const int w = t >> 6, lane = t & 63, lr = lane & 15, lg = lane >> 4;
    const int r0 = rt * 4;
    if (t < 32) {
        bn_coef(statsIn, g2, be2, t, 1.f/25600.f, sc[t], sh[t]);
        ssum[t] = 0.f; ssq[t] = 0.f;
    }
    __syncthreads();
    f32x4 acc[2][3];
    #pragma unroll
    for (int mf = 0; mf < 2; ++mf)
        #pragma unroll
        for (int nf = 0; nf < 3; ++nf)
            acc[mf][nf] = (f32x4){0.f, 0.f, 0.f, 0.f};

    for (int u = t; u < 1152; u += 256) {
        int cg = u / 288, rem = u - cg*288;
        int rr = rem / 48, xx = rem - rr*48;
        int row = r0 + rr;                 // z2p padded row index, <= 45
        uint4 v = {0u,0u,0u,0u};
        if (row >= 2 && row <= 41 && xx >= 2 && xx <= 41) {
            uint4 raw = *(const uint4*)(z2p + ((((size_t)b*4 + cg)*46 + row)*48 + xx)*8);
            unsigned arr[4] = {raw.x, raw.y, raw.z, raw.w};
            ushort h[8];
            #pragma unroll
            for (int e = 0; e < 8; ++e) {
                ushort hv = (e & 1) ? (ushort)(arr[e>>1] >> 16) : (ushort)(arr[e>>1] & 0xffffu);
                float f = fmaxf(fmaf(bf2f(hv), sc[cg*8 + e], sh[cg*8 + e]), 0.f);
                h[e] = f2bf(f);
            }
            v.x = h[0] | ((unsigned)h[1] << 16);
            v.y = h[2] | ((unsigned)h[3] << 16);
            v.z = h[4] | ((unsigned)h[5] << 16);
            v.w = h[6] | ((unsigned)h[7] << 16);
        }
        *(uint4*)(lds + (size_t)u*8) = v;
    }
    __syncthreads();
    #pragma unroll
    for (int kk = 0; kk < 9; ++kk) {
        bf16x8 af[2];
        #pragma unroll
        for (int mf = 0; mf < 2; ++mf)
            af[mf] = *(const bf16x8*)(apck + (size_t)(kk*32 + mf*16 + lr)*32 + lg*8);
        const int ky = kk / 3, kx = kk - ky*3;
        #pragma unroll
        for (int nf = 0; nf < 3; ++nf) {
            bf16x8 bv = *(const bf16x8*)&lds[((lg*6 + (w + ky))*48 + (nf*16 + lr + kx))*8];
            #pragma unroll
            for (int mf = 0; mf < 2; ++mf)
                acc[mf][nf] = __builtin_amdgcn_mfma_f32_16x16x32_bf16(af[mf], bv, acc[mf][nf], 0, 0, 0);
        }
    }
    const int y = r0 + w;
    const int cb = lg*4;
    if (y < 42) {
        float ls[2][4], lq[2][4], br[2][4];
        #pragma unroll
        for (int mf = 0; mf < 2; ++mf)
            #pragma unroll
            for (int i = 0; i < 4; ++i) {
                ls[mf][i] = 0.f; lq[mf][i] = 0.f;
                br[mf][i] = bd1[mf*16 + cb + i];
            }
        #pragma unroll
        for (int nf = 0; nf < 3; ++nf) {
            int x = nf*16 + lr;
            bool xv = (x < 42);
            #pragma unroll
            for (int mf = 0; mf < 2; ++mf) {
                u16x4 pk;
                #pragma unroll
                for (int i = 0; i < 4; ++i) {
                    float v = acc[mf][nf][i] + br[mf][i];
                    if (xv) { ls[mf][i] += v; lq[mf][i] = fmaf(v, v, lq[mf][i]); }
                    pk[i] = f2bf(v);
                }
                if (xv) {
                    int cg1 = mf*2 + (lg >> 1);
                    *(u16x4*)(z3p + ((((size_t)b*4 + cg1)*46 + (y+2))*48 + (x+2))*8 + (lg&1)*4) = pk;
                }
            }
        }
        #pragma unroll
        for (int mf = 0; mf < 2; ++mf)
            #pragma unroll
            for (int i = 0; i < 4; ++i) {
                float s0 = ls[mf][i], q0 = lq[mf][i];
                #pragma unroll
                for (int m = 1; m < 16; m <<= 1) { s0 += __shfl_xor(s0, m, 64); q0 += __shfl_xor(q0, m, 64); }
                if (lr == 0) { atomicAdd(&ssum[mf*16 + cb + i], s0); atomicAdd(&ssq[mf*16 + cb + i], q0); }
            }
    }
    __syncthreads();
    if (t < 32) { atomicAdd(&statsOut[t*2], ssum[t]); atomicAdd(&statsOut[t*2+1], ssq[t]); }
}

// ---------------- dconv2: relu(bn3(z3)) *T wd2 -> sigmoid -> satt. Thread per pixel. ----------------
// FIX: skip taps that fall in the padding region (valid z3 at padded rows/cols 2..43).
__global__ __launch_bounds__(256) void k_dconv2(const ushort* __restrict__ z3p,
                                                const float* __restrict__ wd2,
                                                const float* __restrict__ bd2,
                                                const float* __restrict__ g3,
                                                const float* __restrict__ be3,
                                                const float* __restrict__ stats,
                                                float* __restrict__ satt) {
    __shared__ float sc[32], sh[32], wf[32][9];
    const int b = blockIdx.y, t = threadIdx.x;
    if (t < 32) bn_coef(stats, g3, be3, t, 1.f/28224.f, sc[t], sh[t]);
    for (int u = t; u < 288; u += 256) {
        int c = u / 9, k = u - c*9;
        wf[c][k] = wd2[c*9 + 8 - k];
    }
    __syncthreads();
    const int pix = blockIdx.x * 256 + t;
    if (pix >= P_) return;
    const int y = pix / 44, x = pix - y*44;
    float acc = bd2[0];
    #pragma unroll
    for (int kk = 0; kk < 9; ++kk) {
        int ky = kk / 3, kx = kk - ky*3;
        int ry = y + ky, rx = x + kx;
        if (ry < 2 || ry > 43 || rx < 2 || rx > 43) continue;   // padding -> zero
        #pragma unroll
        for (int cg = 0; cg < 4; ++cg) {
            uint4 raw = *(const uint4*)(z3p + ((((size_t)b*4 + cg)*46 + ry)*48 + rx)*8);
            unsigned arr[4] = {raw.x, raw.y, raw.z, raw.w};
            #pragma unroll
            for (int e = 0; e < 8; ++e) {
                ushort hv = (e & 1) ? (ushort)(arr[e>>1] >> 16) : (ushort)(arr[e>>1] & 0xffffu);
                float f = fmaxf(fmaf(bf2f(hv), sc[cg*8 + e], sh[cg*8 + e]), 0.f);
                acc = fmaf(f, wf[cg*8 + e][kk], acc);
            }
        }
    }
    satt[(size_t)b*P_ + pix] = 1.f / (1.f + expf(-acc));
}

extern "C" void kernel_launch(void* const* d_in, const int* in_sizes, int n_in,
                              void* d_out, int out_size, void* d_ws, size_t ws_size,
                              hipStream_t stream) {
    const float* depth = (const float*)d_in[0];
    const float* rgb   = (const float*)d_in[1];
    const float* w_hc  = (const float*)d_in[2];
    const float* b_hc  = (const float*)d_in[3];
    const float* w_hf  = (const float*)d_in[4];
    const float* b_hf  = (const float*)d_in[5];
    const float* w_s1  = (const float*)d_in[6];
    const float* bs1   = (const float*)d_in[7];
    const float* g1    = (const float*)d_in[8];
    const float* be1   = (const float*)d_in[9];
    const float* w_s2  = (const float*)d_in[10];
    const float* bs2   = (const float*)d_in[11];
    const float* g2    = (const float*)d_in[12];
    const float* be2   = (const float*)d_in[13];
    const float* w_d1  = (const float*)d_in[14];
    const float* bd1   = (const float*)d_in[15];
    const float* g3    = (const float*)d_in[16];
    const float* be3   = (const float*)d_in[17];
    const float* w_d2  = (const float*)d_in[18];
    const float* bd2   = (const float*)d_in[19];
    const float* w_l1  = (const float*)d_in[20];
    const float* bl1   = (const float*)d_in[21];
    const float* w_l2  = (const float*)d_in[22];
    const float* bl2   = (const float*)d_in[23];

    float* out = (float*)d_out;
    float* ws  = (float*)d_ws;

    float* hc    = ws;                    // 1,982,464 f
    float* dT    = hc   + 1982464;        // 1,982,464 f
    float* satt  = dT   + 1982464;        // 30,976 f
    float* catt  = satt + 30976;          // 1,024 f
    float* dcor  = catt + 1024;           // 1,024 f
    float* stats = dcor + 1024;           // 192 f  (3 x 64)
    ushort* wpck  = (ushort*)(stats + 192);   // 147,456 u
    ushort* apck2 = wpck  + 147456;           // 9,216 u
    ushort* apck3 = apck2 + 9216;             // 9,216 u
    ushort* upck  = apck3 + 9216;             // 294,912 u
    ushort* z1p   = upck  + 294912;           // 1,032,192 u  [16][4][42][48][8]
    ushort* z2p   = z1p   + 1032192;          // 1,130,496 u  [16][4][46][48][8]
    ushort* z3p   = z2p   + 1130496;          // 1,130,496 u
    ushort* xpck  = z3p   + 1130496;          // 2,944,000 u

    hipMemsetAsync(stats, 0, 192*sizeof(float), stream);
    hipMemsetAsync(z2p, 0, 1130496*sizeof(ushort), stream);
    hipMemsetAsync(z3p, 0, 1130496*sizeof(ushort), stream);

    k_packw<<<dim3(288,2), 256, 0, stream>>>(w_hc, w_hf, wpck);
    k_packw2<<<36, 256, 0, stream>>>(w_s2, w_d1, apck2, apck3);
    k_packin<<<dim3(16,16), 256, 0, stream>>>(rgb, depth, xpck);
    k_tdepth<<<dim3(31,16), 256, 0, stream>>>(depth, dT);

    k_conv_mfma<<<dim3(11,16), 256, 0, stream>>>(xpck, wpck, b_hc, hc);
    k_dcorr<<<dim3(64,16), 64, 0, stream>>>(rgb, depth, dcor);
    k_mlp<<<16, 64, 0, stream>>>(dcor, w_l1, bl1, w_l2, bl2, catt);
    k_U<<<dim3(32,16), 256, 0, stream>>>(dT, w_s1, upck);

    k_conv1_mfma<<<dim3(11,16), 256, 0, stream>>>(xpck, upck, bs1, z1p, stats);
    k_conv2_mfma<<<dim3(10,16), 256, 0, stream>>>(z1p, apck2, bs2, g1, be1, stats, z2p, stats + 64);
    k_dconv1_mfma<<<dim3(11,16), 256, 0, stream>>>(z2p, apck3, bd1, g2, be2, stats + 64, z3p, stats + 128);
    k_dconv2<<<dim3(8,16), 256, 0, stream>>>(z3p, w_d2, bd2, g3, be3, stats + 128, satt);

    k_packatt<<<dim3(16,16), 256, 0, stream>>>(hc, satt, catt, xpck);
    k_conv_mfma<<<dim3(11,16), 256, 0, stream>>>(xpck, wpck + 73728, b_hf, out);
}